// Round 1
// baseline (193.217 us; speedup 1.0000x reference)
//
#include <hip/hip_runtime.h>
#include <math.h>

// 4 * log(2*pi)
#define L2PI4 7.3515082656373812f

__device__ __forceinline__ float frcp(float x) { return __builtin_amdgcn_rcpf(x); }

// ---------------------------------------------------------------------------
// Kernel A: child parts.
// For each (parent p, side, child-label lc, parent-label lp):
//   out[lp, l_other, c] = logsumexp_k [ gm_scale(child(lc,k), trans(lp,llc,lrc,c)) + cw(lc,k) ]
// left  (side=0): llc = lc, lrc = lo   (trans_mu_lc / trans_var_lc)
// right (side=1): llc = lo, lrc = lc   (trans_mu_rc / trans_var_rc)
// Child layout: cw[node][l][k], cmu/cvar[node][l][k][d].  K is 4 (leaves) or 400.
// lr layout: [p][side][lp][llc][lrc][c]  (p*2+side)*500 + lp*100+llc*20+lrc*4+c
// ---------------------------------------------------------------------------
__global__ __launch_bounds__(256) void kA(
    const float* __restrict__ cw, const float* __restrict__ cmu,
    const float* __restrict__ cvar, int K,
    const float* __restrict__ tmuL, const float* __restrict__ tvarL,
    const float* __restrict__ tmuR, const float* __restrict__ tvarR,
    float* __restrict__ lr)
{
    __shared__ float4 s_cm[400];   // child mu, float4 over d
    __shared__ float4 s_cve[400];  // exp(2*child var)
    __shared__ float  s_cw[400];
    __shared__ float4 s_tm[20];    // trans mu for (lo,c)
    __shared__ float4 s_tve[20];   // exp(2*trans var)

    int pid = blockIdx.x;
    int lp = pid % 5; int t = pid / 5;
    int lc = t % 5;   t /= 5;
    int side = t & 1; int p = t >> 1;
    int cn = 2 * p + side;
    int tid = threadIdx.x;

    const float* cmb = cmu + (size_t)(cn * 5 + lc) * K * 4;
    const float* cvb = cvar + (size_t)(cn * 5 + lc) * K * 4;
    for (int i = tid; i < K * 4; i += 256) {
        ((float*)s_cm)[i]  = cmb[i];
        ((float*)s_cve)[i] = __expf(2.0f * cvb[i]);
    }
    const float* cwb = cw + (size_t)(cn * 5 + lc) * K;
    for (int i = tid; i < K; i += 256) s_cw[i] = cwb[i];

    const float* tm = side ? tmuR : tmuL;
    const float* tv = side ? tvarR : tvarL;
    for (int i = tid; i < 80; i += 256) {
        int o = i >> 2, d = i & 3;
        int lo = o >> 2, c = o & 3;
        int idx = side ? ((((lp * 5 + lo) * 5 + lc) * 4 + c) * 4 + d)
                       : ((((lp * 5 + lc) * 5 + lo) * 4 + c) * 4 + d);
        ((float*)s_tm)[i]  = tm[idx];
        ((float*)s_tve)[i] = __expf(2.0f * tv[idx]);
    }
    __syncthreads();

    int lane = tid & 63, wave = tid >> 6;
    #pragma unroll
    for (int j = 0; j < 5; ++j) {
        int o = wave + 4 * j;               // 0..19 = lo*4 + c
        float4 tmo = s_tm[o];
        float4 tvo = s_tve[o];
        float vals[7];
        #pragma unroll
        for (int i = 0; i < 7; ++i) {
            int k = lane + (i << 6);
            float v = -1e30f;
            if (k < K) {
                float4 cm = s_cm[k];
                float4 ve = s_cve[k];
                float s0 = ve.x + tvo.x, s1 = ve.y + tvo.y;
                float s2 = ve.z + tvo.z, s3 = ve.w + tvo.w;
                float d0 = cm.x - tmo.x, d1 = cm.y - tmo.y;
                float d2 = cm.z - tmo.z, d3 = cm.w - tmo.w;
                float acc = __logf(s0) + d0 * d0 * frcp(s0);
                acc      += __logf(s1) + d1 * d1 * frcp(s1);
                acc      += __logf(s2) + d2 * d2 * frcp(s2);
                acc      += __logf(s3) + d3 * d3 * frcp(s3);
                v = -0.5f * (L2PI4 + acc) + s_cw[k];
            }
            vals[i] = v;
        }
        float M = vals[0];
        #pragma unroll
        for (int i = 1; i < 7; ++i) M = fmaxf(M, vals[i]);
        #pragma unroll
        for (int m = 1; m < 64; m <<= 1) M = fmaxf(M, __shfl_xor(M, m));
        float S = 0.f;
        #pragma unroll
        for (int i = 0; i < 7; ++i) S += __expf(vals[i] - M);
        #pragma unroll
        for (int m = 1; m < 64; m <<= 1) S += __shfl_xor(S, m);
        if (lane == 0) {
            int lo = o >> 2, c = o & 3;
            int llc = side ? lo : lc;
            int lrc = side ? lc : lo;
            lr[((((p * 2 + side) * 5 + lp) * 5 + llc) * 5 + lrc) * 4 + c] =
                M + __logf(S);
        }
    }
}

// ---------------------------------------------------------------------------
// Kernel B: combine left+right+trans_weight, score against parent state via
// gm_full, emit new w/mu/var for the parent node (K' = 400).
// Output flatten order matches reference: kout = ((llc*5+lrc)*4+ks)*4 + c
// ---------------------------------------------------------------------------
__global__ __launch_bounds__(256) void kB(
    const float* __restrict__ lr,
    const float* __restrict__ tw,
    const float* __restrict__ tmu_p, const float* __restrict__ tvar_p,
    const float* __restrict__ sw_all, const float* __restrict__ smu,
    const float* __restrict__ svar, int off,
    float* __restrict__ wo, float* __restrict__ muo, float* __restrict__ varo)
{
    int p = blockIdx.x, tid = threadIdx.x;
    __shared__ float s_cs[500];
    __shared__ float s_tm[2000], s_tv[2000], s_tve[2000];
    __shared__ float s_sw[20], s_sm[80], s_sv[80], s_sve[80];

    for (int i = tid; i < 500; i += 256)
        s_cs[i] = lr[(p * 2) * 500 + i] + lr[(p * 2 + 1) * 500 + i] + tw[i];
    for (int i = tid; i < 2000; i += 256) {
        s_tm[i] = tmu_p[i];
        float v = tvar_p[i];
        s_tv[i] = v;
        s_tve[i] = __expf(2.0f * v);
    }
    int node = off + p;
    for (int i = tid; i < 20; i += 256) s_sw[i] = sw_all[node * 20 + i];
    for (int i = tid; i < 80; i += 256) {
        s_sm[i] = smu[node * 80 + i];
        float v = svar[node * 80 + i];
        s_sv[i] = v;
        s_sve[i] = __expf(2.0f * v);
    }
    __syncthreads();

    for (int e = tid; e < 2000; e += 256) {
        int c = e & 3;
        int ks = (e >> 2) & 3;
        int r = e >> 4;            // lp*25 + llc*5 + lrc
        int lrc = r % 5; int r2 = r / 5;
        int llc = r2 % 5; int lp = r2 / 5;
        int t4 = ((lp * 5 + llc) * 5 + lrc) * 4 + c;   // 0..499
        int sidx = (lp * 4 + ks) * 4;

        float scale = 0.f;
        float pmu[4], pvar[4];
        #pragma unroll
        for (int d = 0; d < 4; ++d) {
            float m1 = s_sm[sidx + d], v1 = s_sv[sidx + d], v1s = s_sve[sidx + d];
            float m2 = s_tm[t4 * 4 + d], v2 = s_tv[t4 * 4 + d], v2s = s_tve[t4 * 4 + d];
            float s  = v1s + v2s;
            float rs = frcp(s);
            float ls = __logf(s);
            float df = m1 - m2;
            scale  += ls + df * df * rs;
            pmu[d]  = (m1 * v2s + m2 * v1s) * rs;
            pvar[d] = v1 + v2 - 0.5f * ls;
        }
        float w = -0.5f * (L2PI4 + scale) + s_cs[t4] + s_sw[lp * 4 + ks];
        int kout = ((llc * 5 + lrc) * 4 + ks) * 4 + c;
        size_t ob = (size_t)(p * 5 + lp) * 400 + kout;
        wo[ob] = w;
        #pragma unroll
        for (int d = 0; d < 4; ++d) {
            muo[ob * 4 + d]  = pmu[d];
            varo[ob * 4 + d] = pvar[d];
        }
    }
}

// ---------------------------------------------------------------------------
// Launcher: 7 levels, ping-pong node buffers in d_ws.
// ws layout (floats):
//   lr    [64000]           left/right parts, reused per level
//   Aw    [128000]  Amu [512000]  Avar [512000]   (64-node buffer)
//   Bw    [64000]   Bmu [256000]  Bvar [256000]   (32-node buffer)
// total 1,792,000 floats = ~6.9 MB
// ---------------------------------------------------------------------------
extern "C" void kernel_launch(void* const* d_in, const int* in_sizes, int n_in,
                              void* d_out, int out_size, void* d_ws, size_t ws_size,
                              hipStream_t stream) {
    (void)in_sizes; (void)n_in; (void)out_size; (void)ws_size;
    const float* sw      = (const float*)d_in[0];
    const float* smu     = (const float*)d_in[1];
    const float* svar    = (const float*)d_in[2];
    const float* tw      = (const float*)d_in[3];
    const float* tmu_p   = (const float*)d_in[4];
    const float* tmu_lc  = (const float*)d_in[5];
    const float* tmu_rc  = (const float*)d_in[6];
    const float* tvar_p  = (const float*)d_in[7];
    const float* tvar_lc = (const float*)d_in[8];
    const float* tvar_rc = (const float*)d_in[9];

    float* ws   = (float*)d_ws;
    float* lr   = ws;               // 64000
    float* Aw   = lr + 64000;       // 128000
    float* Amu  = Aw + 128000;      // 512000
    float* Avar = Amu + 512000;     // 512000
    float* Bw   = Avar + 512000;    // 64000
    float* Bmu  = Bw + 64000;       // 256000
    float* Bvar = Bmu + 256000;     // 256000
    float* out  = (float*)d_out;

    // Level 1: m=64, children are leaves (K=4) straight from state arrays.
    hipLaunchKernelGGL(kA, dim3(64 * 50), dim3(256), 0, stream,
                       sw, smu, svar, 4, tmu_lc, tvar_lc, tmu_rc, tvar_rc, lr);
    hipLaunchKernelGGL(kB, dim3(64), dim3(256), 0, stream,
                       lr, tw, tmu_p, tvar_p, sw, smu, svar, 128, Aw, Amu, Avar);

    float *cwp = Aw, *cmup = Amu, *cvarp = Avar;
    float *owp = Bw, *omup = Bmu, *ovarp = Bvar;
    int off = 192;
    for (int m = 32; m >= 1; m >>= 1) {
        float* dw  = (m == 1) ? out          : owp;
        float* dmu = (m == 1) ? out + 2000   : omup;
        float* dvr = (m == 1) ? out + 10000  : ovarp;
        hipLaunchKernelGGL(kA, dim3(m * 50), dim3(256), 0, stream,
                           cwp, cmup, cvarp, 400, tmu_lc, tvar_lc, tmu_rc, tvar_rc, lr);
        hipLaunchKernelGGL(kB, dim3(m), dim3(256), 0, stream,
                           lr, tw, tmu_p, tvar_p, sw, smu, svar, off, dw, dmu, dvr);
        off += m;
        float* t;
        t = cwp;  cwp  = owp;  owp  = t;
        t = cmup; cmup = omup; omup = t;
        t = cvarp; cvarp = ovarp; ovarp = t;
    }
}

// Round 2
// 138.116 us; speedup vs baseline: 1.3989x; 1.3989x over previous
//
#include <hip/hip_runtime.h>
#include <math.h>

#define L2PI4      7.3515082656373812f   // 4*log(2*pi)
#define HALF_L2PI4 3.6757541328186906f   // 2*log(2*pi)

__device__ __forceinline__ float frcp(float x) { return __builtin_amdgcn_rcpf(x); }

// ---------------------------------------------------------------------------
// kP: precompute exp(2*trans_var_*) tables (2000 elems each).
// ---------------------------------------------------------------------------
__global__ __launch_bounds__(256) void kP(
    const float* __restrict__ a, const float* __restrict__ b,
    const float* __restrict__ c,
    float* __restrict__ oa, float* __restrict__ ob, float* __restrict__ oc)
{
    int i = blockIdx.x * 256 + threadIdx.x;
    if (i < 2000) {
        oa[i] = __expf(2.0f * a[i]);
        ob[i] = __expf(2.0f * b[i]);
        oc[i] = __expf(2.0f * c[i]);
    }
}

// ---------------------------------------------------------------------------
// kA1: level-1 child parts (children are leaves, K=4).
// One output per thread, serial logsumexp over 4 components.
// block = child node cn = 2p+side; 500 outputs (lc,lp,lo,c) per block.
// ---------------------------------------------------------------------------
__global__ __launch_bounds__(256) void kA1(
    const float* __restrict__ sw, const float* __restrict__ smu,
    const float* __restrict__ svar,
    const float* __restrict__ tmuL, const float* __restrict__ tveL,
    const float* __restrict__ tmuR, const float* __restrict__ tveR,
    float* __restrict__ lr)
{
    int b = blockIdx.x;            // cn = 2p + side
    int side = b & 1;
    int tid = threadIdx.x;
    __shared__ float s_cm[80], s_cve[80], s_cw[20];
    if (tid < 80) {
        s_cm[tid]  = smu[b * 80 + tid];
        s_cve[tid] = __expf(2.0f * svar[b * 80 + tid]);
        if (tid < 20) s_cw[tid] = sw[b * 20 + tid] - HALF_L2PI4;
    }
    __syncthreads();
    const float4* tm = (const float4*)(side ? tmuR : tmuL);
    const float4* tv = (const float4*)(side ? tveR : tveL);
    for (int e = tid; e < 500; e += 256) {
        int c = e & 3, r = e >> 2;        // r = lc*25 + lp*5 + lo
        int lo = r % 5, r2 = r / 5, lp = r2 % 5, lc = r2 / 5;
        int idx = side ? (((lp * 5 + lo) * 5 + lc) * 4 + c)
                       : (((lp * 5 + lc) * 5 + lo) * 4 + c);
        float4 tmo = tm[idx], tvo = tv[idx];
        float vals[4];
        #pragma unroll
        for (int k = 0; k < 4; ++k) {
            int ci = (lc * 4 + k) * 4;
            float s0 = s_cve[ci + 0] + tvo.x, s1 = s_cve[ci + 1] + tvo.y;
            float s2 = s_cve[ci + 2] + tvo.z, s3 = s_cve[ci + 3] + tvo.w;
            float d0 = s_cm[ci + 0] - tmo.x, d1 = s_cm[ci + 1] - tmo.y;
            float d2 = s_cm[ci + 2] - tmo.z, d3 = s_cm[ci + 3] - tmo.w;
            float p01 = s0 * s1, p23 = s2 * s3;
            float q01 = fmaf(d0 * d0, s1, d1 * d1 * s0);
            float q23 = fmaf(d2 * d2, s3, d3 * d3 * s2);
            float P = p01 * p23;
            float Q = fmaf(q01, p23, q23 * p01);
            vals[k] = fmaf(-0.5f, __logf(P) + Q * frcp(P), s_cw[lc * 4 + k]);
        }
        float M = fmaxf(fmaxf(vals[0], vals[1]), fmaxf(vals[2], vals[3]));
        float S = __expf(vals[0] - M) + __expf(vals[1] - M)
                + __expf(vals[2] - M) + __expf(vals[3] - M);
        lr[(size_t)b * 500 + idx] = M + __logf(S);
    }
}

// ---------------------------------------------------------------------------
// kA: child parts for K=400 levels. block=(p,side,lc,lp), 4 waves.
// Child fragment register-cached per lane (coalesced global loads, no LDS).
// Fused 1-log/1-rcp per pair. Padding k>=400 via w=-1e30.
// ---------------------------------------------------------------------------
__global__ __launch_bounds__(256) void kA(
    const float* __restrict__ cw, const float* __restrict__ cmu,
    const float* __restrict__ cvar,
    const float* __restrict__ tmuL, const float* __restrict__ tveL,
    const float* __restrict__ tmuR, const float* __restrict__ tveR,
    float* __restrict__ lr)
{
    int pid = blockIdx.x;
    int lp = pid % 5, t = pid / 5;
    int lc = t % 5;   t /= 5;
    int side = t & 1, p = t >> 1;
    int cn = 2 * p + side;
    int tid = threadIdx.x, lane = tid & 63, wave = tid >> 6;

    const float4* cmb = (const float4*)(cmu + (size_t)(cn * 5 + lc) * 1600);
    const float4* cvb = (const float4*)(cvar + (size_t)(cn * 5 + lc) * 1600);
    const float*  cwb = cw + (size_t)(cn * 5 + lc) * 400;

    float4 cm[7], cve[7];
    float  cwr[7];
    #pragma unroll
    for (int i = 0; i < 7; ++i) {
        int k = lane + (i << 6);
        if (k < 400) {
            float4 m = cmb[k], v = cvb[k];
            cm[i] = m;
            cve[i] = make_float4(__expf(2.f * v.x), __expf(2.f * v.y),
                                 __expf(2.f * v.z), __expf(2.f * v.w));
            cwr[i] = cwb[k] - HALF_L2PI4;
        } else {
            cm[i]  = make_float4(0.f, 0.f, 0.f, 0.f);
            cve[i] = make_float4(1.f, 1.f, 1.f, 1.f);
            cwr[i] = -1e30f;
        }
    }

    const float4* tm = (const float4*)(side ? tmuR : tmuL);
    const float4* tv = (const float4*)(side ? tveR : tveL);
    size_t lrb = (size_t)(p * 2 + side) * 500;

    for (int j = 0; j < 5; ++j) {
        int o = wave * 5 + j;             // 0..19 = lo*4 + c
        int lo = o >> 2, c = o & 3;
        int idx = side ? (((lp * 5 + lo) * 5 + lc) * 4 + c)
                       : (((lp * 5 + lc) * 5 + lo) * 4 + c);
        float4 tmo = tm[idx], tvo = tv[idx];
        float vals[7];
        #pragma unroll
        for (int i = 0; i < 7; ++i) {
            float s0 = cve[i].x + tvo.x, s1 = cve[i].y + tvo.y;
            float s2 = cve[i].z + tvo.z, s3 = cve[i].w + tvo.w;
            float d0 = cm[i].x - tmo.x, d1 = cm[i].y - tmo.y;
            float d2 = cm[i].z - tmo.z, d3 = cm[i].w - tmo.w;
            float p01 = s0 * s1, p23 = s2 * s3;
            float q01 = fmaf(d0 * d0, s1, d1 * d1 * s0);
            float q23 = fmaf(d2 * d2, s3, d3 * d3 * s2);
            float P = p01 * p23;
            float Q = fmaf(q01, p23, q23 * p01);
            vals[i] = fmaf(-0.5f, __logf(P) + Q * frcp(P), cwr[i]);
        }
        float M = vals[0];
        #pragma unroll
        for (int i = 1; i < 7; ++i) M = fmaxf(M, vals[i]);
        #pragma unroll
        for (int s = 32; s; s >>= 1) M = fmaxf(M, __shfl_xor(M, s));
        float S = 0.f;
        #pragma unroll
        for (int i = 0; i < 7; ++i) S += __expf(vals[i] - M);
        #pragma unroll
        for (int s = 32; s; s >>= 1) S += __shfl_xor(S, s);
        if (lane == 0) lr[lrb + idx] = M + __logf(S);
    }
}

// ---------------------------------------------------------------------------
// kB: combine left+right+tw, score vs parent state (gm_full), emit w/mu/var.
// No trans LDS staging; coalesced float4 loads/stores (ob = p*2000 + e).
// ---------------------------------------------------------------------------
__global__ __launch_bounds__(256) void kB(
    const float* __restrict__ lr, const float* __restrict__ tw,
    const float* __restrict__ tmu_p, const float* __restrict__ tvar_p,
    const float* __restrict__ tve_p,
    const float* __restrict__ sw_all, const float* __restrict__ smu,
    const float* __restrict__ svar, int off,
    float* __restrict__ wo, float* __restrict__ muo, float* __restrict__ varo)
{
    int p = blockIdx.x, tid = threadIdx.x;
    int node = off + p;
    __shared__ float s_sw[20], s_sm[80], s_sv[80], s_sve[80];
    if (tid < 80) {
        s_sm[tid] = smu[node * 80 + tid];
        float v = svar[node * 80 + tid];
        s_sv[tid] = v;
        s_sve[tid] = __expf(2.0f * v);
        if (tid < 20) s_sw[tid] = sw_all[node * 20 + tid];
    }
    __syncthreads();
    const float4* tm4 = (const float4*)tmu_p;
    const float4* tv4 = (const float4*)tvar_p;
    const float4* te4 = (const float4*)tve_p;
    const float* lrL = lr + (size_t)p * 1000;
    const float* lrR = lrL + 500;
    for (int e = tid; e < 2000; e += 256) {
        int c = e & 3, ks = (e >> 2) & 3, r = e >> 4;
        int lrc = r % 5, r2 = r / 5, llc = r2 % 5, lp = r2 / 5;
        int t4 = ((lp * 5 + llc) * 5 + lrc) * 4 + c;
        float cs = lrL[t4] + lrR[t4] + tw[t4];
        float4 m2 = tm4[t4], v2 = tv4[t4], e2 = te4[t4];
        int sidx = (lp * 4 + ks) * 4;
        float base = cs + s_sw[lp * 4 + ks] - HALF_L2PI4;
        float scale = 0.f;
        float4 pmu, pvar;
        {
            float v1s = s_sve[sidx + 0], s = v1s + e2.x, rs = frcp(s), ls = __logf(s);
            float m1 = s_sm[sidx + 0], df = m1 - m2.x;
            scale += ls + df * df * rs;
            pmu.x  = (m1 * e2.x + m2.x * v1s) * rs;
            pvar.x = s_sv[sidx + 0] + v2.x - 0.5f * ls;
        }
        {
            float v1s = s_sve[sidx + 1], s = v1s + e2.y, rs = frcp(s), ls = __logf(s);
            float m1 = s_sm[sidx + 1], df = m1 - m2.y;
            scale += ls + df * df * rs;
            pmu.y  = (m1 * e2.y + m2.y * v1s) * rs;
            pvar.y = s_sv[sidx + 1] + v2.y - 0.5f * ls;
        }
        {
            float v1s = s_sve[sidx + 2], s = v1s + e2.z, rs = frcp(s), ls = __logf(s);
            float m1 = s_sm[sidx + 2], df = m1 - m2.z;
            scale += ls + df * df * rs;
            pmu.z  = (m1 * e2.z + m2.z * v1s) * rs;
            pvar.z = s_sv[sidx + 2] + v2.z - 0.5f * ls;
        }
        {
            float v1s = s_sve[sidx + 3], s = v1s + e2.w, rs = frcp(s), ls = __logf(s);
            float m1 = s_sm[sidx + 3], df = m1 - m2.w;
            scale += ls + df * df * rs;
            pmu.w  = (m1 * e2.w + m2.w * v1s) * rs;
            pvar.w = s_sv[sidx + 3] + v2.w - 0.5f * ls;
        }
        float w = fmaf(-0.5f, scale, base);
        size_t ob = (size_t)p * 2000 + e;
        wo[ob] = w;
        ((float4*)muo)[ob]  = pmu;
        ((float4*)varo)[ob] = pvar;
    }
}

// ---------------------------------------------------------------------------
// Launcher. ws layout (floats):
//   lr[64000] Aw[128000] Amu[512000] Avar[512000]
//   Bw[64000] Bmu[256000] Bvar[256000] tveL[2000] tveR[2000] tveP[2000]
// ---------------------------------------------------------------------------
extern "C" void kernel_launch(void* const* d_in, const int* in_sizes, int n_in,
                              void* d_out, int out_size, void* d_ws, size_t ws_size,
                              hipStream_t stream) {
    (void)in_sizes; (void)n_in; (void)out_size; (void)ws_size;
    const float* sw      = (const float*)d_in[0];
    const float* smu     = (const float*)d_in[1];
    const float* svar    = (const float*)d_in[2];
    const float* tw      = (const float*)d_in[3];
    const float* tmu_p   = (const float*)d_in[4];
    const float* tmu_lc  = (const float*)d_in[5];
    const float* tmu_rc  = (const float*)d_in[6];
    const float* tvar_p  = (const float*)d_in[7];
    const float* tvar_lc = (const float*)d_in[8];
    const float* tvar_rc = (const float*)d_in[9];

    float* ws   = (float*)d_ws;
    float* lr   = ws;
    float* Aw   = lr + 64000;
    float* Amu  = Aw + 128000;
    float* Avar = Amu + 512000;
    float* Bw   = Avar + 512000;
    float* Bmu  = Bw + 64000;
    float* Bvar = Bmu + 256000;
    float* tveL = Bvar + 256000;
    float* tveR = tveL + 2000;
    float* tveP = tveR + 2000;
    float* out  = (float*)d_out;

    hipLaunchKernelGGL(kP, dim3(8), dim3(256), 0, stream,
                       tvar_lc, tvar_rc, tvar_p, tveL, tveR, tveP);

    // Level 1: m=64, children are leaves (K=4).
    hipLaunchKernelGGL(kA1, dim3(128), dim3(256), 0, stream,
                       sw, smu, svar, tmu_lc, tveL, tmu_rc, tveR, lr);
    hipLaunchKernelGGL(kB, dim3(64), dim3(256), 0, stream,
                       lr, tw, tmu_p, tvar_p, tveP, sw, smu, svar, 128, Aw, Amu, Avar);

    float *cwp = Aw, *cmup = Amu, *cvarp = Avar;
    float *owp = Bw, *omup = Bmu, *ovarp = Bvar;
    int off = 192;
    for (int m = 32; m >= 1; m >>= 1) {
        float* dw  = (m == 1) ? out         : owp;
        float* dmu = (m == 1) ? out + 2000  : omup;
        float* dvr = (m == 1) ? out + 10000 : ovarp;
        hipLaunchKernelGGL(kA, dim3(m * 50), dim3(256), 0, stream,
                           cwp, cmup, cvarp, tmu_lc, tveL, tmu_rc, tveR, lr);
        hipLaunchKernelGGL(kB, dim3(m), dim3(256), 0, stream,
                           lr, tw, tmu_p, tvar_p, tveP, sw, smu, svar, off, dw, dmu, dvr);
        off += m;
        float* t;
        t = cwp;  cwp  = owp;  owp  = t;
        t = cmup; cmup = omup; omup = t;
        t = cvarp; cvarp = ovarp; ovarp = t;
    }
}